// Round 5
// baseline (139.376 us; speedup 1.0000x reference)
//
#include <hip/hip_runtime.h>

#define IN_N   4096
#define OW     4084          // (4096 + 2*1 - 15) + 1
#define KS     15
#define TILE   64            // 64x64 output tile per block (4 waves x 16 rows)
#define XROWS  78            // TILE + KS - 1
#define XS     88            // LDS row stride (halfwords); frags stay 16B-aligned
#define NBX    64
#define NBY    64

typedef __attribute__((ext_vector_type(8))) short v8s;   // 8 x bf16 frag
typedef __attribute__((ext_vector_type(4))) float v4f;   // C/D frag

__device__ __forceinline__ unsigned short f2bf(float f) {
    union { float f; unsigned u; } c; c.f = f;
    unsigned r = c.u + 0x7fff + ((c.u >> 16) & 1);   // RTNE (inputs finite)
    return (unsigned short)(r >> 16);
}
__device__ __forceinline__ unsigned pack2(float a, float b) {
    return (unsigned)f2bf(a) | ((unsigned)f2bf(b) << 16);
}

// ---- pre-kernel: build the 15 banded-B MFMA fragments once into d_ws ----
// B_ky[k][n] = w[ky, k-n] if 0 <= k-n < 15 else 0
// lane e holds B[k = (e>>4)*8 + j][n = e&15], j = 0..7
__global__ void build_B(const float* __restrict__ w, unsigned short* __restrict__ Bg) {
    int ky = blockIdx.x, e = threadIdx.x;
    int n = e & 15, quad = e >> 4;
    unsigned short vals[8];
    #pragma unroll
    for (int j = 0; j < 8; ++j) {
        int d = quad * 8 + j - n;
        vals[j] = (d >= 0 && d < KS) ? f2bf(w[ky * KS + d]) : (unsigned short)0;
    }
    *(v8s*)(&Bg[(ky * 64 + e) * 8]) = *(const v8s*)vals;
}

// 8 blocks/CU: LDS 13.8KB (<20KB), VGPR must stay <=64. TLP is the
// latency-hiding mechanism here (R4 post-mortem: pipelining that costs
// occupancy is a net loss).
__global__ __launch_bounds__(256, 8) void conv2d_mfma4(
    const float* __restrict__ x, const unsigned short* __restrict__ Bg,
    const float* __restrict__ bias, float* __restrict__ out)
{
    __shared__ unsigned short xtile[XROWS * XS] __attribute__((aligned(16)));

    const int tid = threadIdx.x;
    const int bx = blockIdx.x, by = blockIdx.y;
    const int X0 = bx * TILE;
    const int Y0 = by * TILE;

    // ---- stage input tile fp32 -> bf16 ----
    // 20 float4-cols x 12 rows = 240 active threads, 7 row-passes (last: 6 rows)
    const int tx = tid % 20;     // float4 column: cols 4*tx .. 4*tx+3 of [0,80)
    const int ty = tid / 20;     // 0..12 (ty==12 -> idle)
    const bool interior = (bx > 0) & (bx < NBX - 1) & (by > 0) & (by < NBY - 1);

    if (ty < 12) {
        if (interior) {
            const float4* xr = (const float4*)(x + (size_t)(Y0 - 1 + ty) * IN_N + (X0 - 1 + 4 * tx));
            // note: X0-1+4tx is 4B-aligned only as float; use unaligned-safe loads
            const float* xs = (const float*)xr;
            unsigned* dst = (unsigned*)&xtile[ty * XS + 4 * tx];
            #pragma unroll
            for (int i = 0; i < 7; ++i) {
                int row = ty + 12 * i;
                if (row >= XROWS) break;
                float f0 = xs[0], f1 = xs[1], f2 = xs[2], f3 = xs[3];
                dst[0] = pack2(f0, f1);
                dst[1] = pack2(f2, f3);
                xs  += 12 * (size_t)IN_N;
                dst += 6 * XS;               // 12 rows = 6*XS dwords
            }
        } else {
            const int gc0 = X0 - 1 + 4 * tx;
            unsigned* dst = (unsigned*)&xtile[ty * XS + 4 * tx];
            #pragma unroll
            for (int i = 0; i < 7; ++i) {
                int row = ty + 12 * i;
                if (row >= XROWS) break;
                int gr = Y0 - 1 + row;
                float f[4] = {0.f, 0.f, 0.f, 0.f};
                if ((unsigned)gr < (unsigned)IN_N) {
                    const float* xr = x + (size_t)gr * IN_N;
                    #pragma unroll
                    for (int c = 0; c < 4; ++c)
                        if ((unsigned)(gc0 + c) < (unsigned)IN_N) f[c] = xr[gc0 + c];
                }
                dst[0] = pack2(f[0], f[1]);
                dst[1] = pack2(f[2], f[3]);
                dst += 6 * XS;
            }
        }
    }
    __syncthreads();

    // ---- MFMA main loop ----
    const int lane = tid & 63;
    const int wv   = tid >> 6;
    const int m    = lane & 15;
    const int quad = lane >> 4;

    v4f acc[4];
    #pragma unroll
    for (int t = 0; t < 4; ++t) acc[t] = (v4f){0.f, 0.f, 0.f, 0.f};

    const v8s* Bgv = (const v8s*)Bg;
    v8s bcur = Bgv[lane];                           // ky = 0 (L2-resident)
    const unsigned short* arow = &xtile[(wv * 16 + m) * XS + quad * 8];

    #pragma unroll
    for (int ky = 0; ky < KS; ++ky) {
        v8s bnext = (ky < KS - 1) ? Bgv[(ky + 1) * 64 + lane] : bcur;
        v8s a0 = *(const v8s*)(arow + 0);
        v8s a1 = *(const v8s*)(arow + 16);
        v8s a2 = *(const v8s*)(arow + 32);
        v8s a3 = *(const v8s*)(arow + 48);
        acc[0] = __builtin_amdgcn_mfma_f32_16x16x32_bf16(a0, bcur, acc[0], 0, 0, 0);
        acc[1] = __builtin_amdgcn_mfma_f32_16x16x32_bf16(a1, bcur, acc[1], 0, 0, 0);
        acc[2] = __builtin_amdgcn_mfma_f32_16x16x32_bf16(a2, bcur, acc[2], 0, 0, 0);
        acc[3] = __builtin_amdgcn_mfma_f32_16x16x32_bf16(a3, bcur, acc[3], 0, 0, 0);
        arow += XS;
        bcur = bnext;
    }

    // ---- epilogue: D row = quad*4 + r, col = m + t*16 ----
    const float bv = bias[0];
    const int orow0 = Y0 + wv * 16 + quad * 4;
    const int ocol0 = X0 + m;
    if ((bx < NBX - 1) & (by < NBY - 1)) {
        float* o0 = &out[(size_t)orow0 * OW + ocol0];
        #pragma unroll
        for (int t = 0; t < 4; ++t)
            #pragma unroll
            for (int r = 0; r < 4; ++r)
                o0[(size_t)r * OW + t * 16] = acc[t][r] + bv;
    } else {
        #pragma unroll
        for (int t = 0; t < 4; ++t) {
            int oc = ocol0 + t * 16;
            if (oc < OW) {
                #pragma unroll
                for (int r = 0; r < 4; ++r) {
                    int orow = orow0 + r;
                    if (orow < OW)
                        out[(size_t)orow * OW + oc] = acc[t][r] + bv;
                }
            }
        }
    }
}

extern "C" void kernel_launch(void* const* d_in, const int* in_sizes, int n_in,
                              void* d_out, int out_size, void* d_ws, size_t ws_size,
                              hipStream_t stream) {
    const float* x    = (const float*)d_in[0];
    const float* w    = (const float*)d_in[1];
    const float* bias = (const float*)d_in[2];
    float* out        = (float*)d_out;
    unsigned short* Bg = (unsigned short*)d_ws;     // 15 KiB scratch

    build_B<<<dim3(KS), dim3(64), 0, stream>>>(w, Bg);
    dim3 grid(NBX, NBY);                            // 64 x 64 = 4096 blocks
    conv2d_mfma4<<<grid, dim3(256), 0, stream>>>(x, Bg, bias, out);
}